// Round 1
// baseline (1408.588 us; speedup 1.0000x reference)
//
#include <hip/hip_runtime.h>
#include <hip/hip_bf16.h>
#include <stdint.h>

// BitLinear forward on MI355X:
//   C[m,n] = (s_m * wscale) * sum_k q[m,k] * t[n,k]
//   q in int8 [-8,7] (per-token int4 quant), t in {-1,0,1} (ternary weights)
// Exact int32 accumulation via v_mfma_i32_16x16x64_i8.
//
// M = 4*2048 = 8192, N = 16384, K = 4096.

#define K_DIM 4096
#define M_DIM 8192
#define N_DIM 16384

typedef int v4i __attribute__((ext_vector_type(4)));

typedef __attribute__((address_space(1))) void gvoid_t;
typedef __attribute__((address_space(3))) void lvoid_t;

__device__ __forceinline__ void gl_lds16(const void* g, void* l) {
    // async global->LDS, 16B per lane; LDS dest is wave-uniform base + lane*16
    __builtin_amdgcn_global_load_lds((gvoid_t*)(void*)g, (lvoid_t*)l, 16, 0, 0);
}

// ---------------- Phase 1a: partial sums of |w| ----------------
__global__ __launch_bounds__(256) void wabs_partial_k(const float* __restrict__ w,
                                                      double* __restrict__ part) {
    const long n4 = (long)N_DIM * K_DIM / 4;  // 16,777,216 float4s
    long i = (long)blockIdx.x * blockDim.x + threadIdx.x;
    const long stride = (long)gridDim.x * blockDim.x;
    const float4* w4 = (const float4*)w;
    double s = 0.0;
    for (; i < n4; i += stride) {
        float4 v = w4[i];
        s += (double)fabsf(v.x);
        s += (double)fabsf(v.y);
        s += (double)fabsf(v.z);
        s += (double)fabsf(v.w);
    }
    __shared__ double red[256];
    const int tid = threadIdx.x;
    red[tid] = s;
    __syncthreads();
    for (int w2 = 128; w2 > 0; w2 >>= 1) {
        if (tid < w2) red[tid] += red[tid + w2];
        __syncthreads();
    }
    if (tid == 0) part[blockIdx.x] = red[0];
}

// ---------------- Phase 1b: final mean -> wscale ----------------
__global__ __launch_bounds__(256) void wscale_final_k(const double* __restrict__ part,
                                                      float* __restrict__ wscale) {
    __shared__ double red[256];
    const int tid = threadIdx.x;
    double s = 0.0;
    for (int i = tid; i < 1024; i += 256) s += part[i];
    red[tid] = s;
    __syncthreads();
    for (int w2 = 128; w2 > 0; w2 >>= 1) {
        if (tid < w2) red[tid] += red[tid + w2];
        __syncthreads();
    }
    if (tid == 0) {
        double mean = red[0] / (double)((long)N_DIM * K_DIM);
        *wscale = fmaxf((float)mean, 1e-5f);
    }
}

// ---------------- Phase 2: ternary-quantize weights ----------------
__global__ __launch_bounds__(256) void wquant_k(const float* __restrict__ w,
                                                signed char* __restrict__ qw,
                                                const float* __restrict__ wscale) {
    const float sc = *wscale;
    const long i = (long)blockIdx.x * 256 + threadIdx.x;  // one thread per 16 elems
    const float4* w4 = (const float4*)(w + i * 16);
    union { signed char c[16]; int4 v; } u;
#pragma unroll
    for (int j = 0; j < 4; ++j) {
        float4 v = w4[j];
        u.c[j * 4 + 0] = (signed char)fminf(fmaxf(rintf(v.x / sc), -1.f), 1.f);
        u.c[j * 4 + 1] = (signed char)fminf(fmaxf(rintf(v.y / sc), -1.f), 1.f);
        u.c[j * 4 + 2] = (signed char)fminf(fmaxf(rintf(v.z / sc), -1.f), 1.f);
        u.c[j * 4 + 3] = (signed char)fminf(fmaxf(rintf(v.w / sc), -1.f), 1.f);
    }
    *(int4*)(qw + i * 16) = u.v;
}

// ---------------- Phase 3: per-token absmax quant of x ----------------
__global__ __launch_bounds__(256) void xquant_k(const float* __restrict__ x,
                                                signed char* __restrict__ qx,
                                                float* __restrict__ sx,
                                                const float* __restrict__ wscale) {
    const int row = blockIdx.x;       // 0..8191
    const int tid = threadIdx.x;
    const float4* xr = (const float4*)(x + (long)row * K_DIM) + tid * 4;
    float4 v[4];
    float am = 0.f;
#pragma unroll
    for (int j = 0; j < 4; ++j) {
        v[j] = xr[j];
        am = fmaxf(am, fmaxf(fmaxf(fabsf(v[j].x), fabsf(v[j].y)),
                             fmaxf(fabsf(v[j].z), fabsf(v[j].w))));
    }
#pragma unroll
    for (int off = 32; off > 0; off >>= 1) am = fmaxf(am, __shfl_down(am, off));
    __shared__ float wm[4];
    if ((tid & 63) == 0) wm[tid >> 6] = am;
    __syncthreads();
    am = fmaxf(fmaxf(wm[0], wm[1]), fmaxf(wm[2], wm[3]));
    const float s = fmaxf(am, 1e-5f) / 7.0f;   // identical fp32 ops to reference
    union { signed char c[16]; int4 q; } u;
#pragma unroll
    for (int j = 0; j < 4; ++j) {
        u.c[j * 4 + 0] = (signed char)fminf(fmaxf(rintf(v[j].x / s), -8.f), 7.f);
        u.c[j * 4 + 1] = (signed char)fminf(fmaxf(rintf(v[j].y / s), -8.f), 7.f);
        u.c[j * 4 + 2] = (signed char)fminf(fmaxf(rintf(v[j].z / s), -8.f), 7.f);
        u.c[j * 4 + 3] = (signed char)fminf(fmaxf(rintf(v[j].w / s), -8.f), 7.f);
    }
    *(int4*)(qx + (long)row * K_DIM + tid * 16) = u.q;
    if (tid == 0) sx[row] = s * (*wscale);     // fused output scale
}

// ---------------- Phase 4: int8 GEMM (128x128 tile, BK=64) ----------------
// A = qx (MxK row-major), B = qw (NxK row-major, i.e. B^T GEMM).
// 4 waves, each computes 64x64 via 4x4 grid of 16x16x64 i8 MFMAs.
// LDS swizzle: chunk for (row r, kgroup q) at byte offset r*64 + ((q+(r>>1))&3)*16
// -> 2-way bank aliasing on ds_read_b128 (free), compatible with global_load_lds.
__global__ __launch_bounds__(256) void gemm_k(const signed char* __restrict__ qx,
                                              const signed char* __restrict__ qw,
                                              const float* __restrict__ sx,
                                              float* __restrict__ out) {
    __shared__ signed char lA[128 * 64];
    __shared__ signed char lB[128 * 64];

    const int tid  = threadIdx.x;
    const int lane = tid & 63;
    const int wave = tid >> 6;
    const int m0 = blockIdx.x * 128;
    const int n0 = blockIdx.y * 128;
    const int wr = (wave >> 1) * 64;
    const int wc = (wave & 1) * 64;

    // staging: 512 chunks of 16B per tile; thread stages chunks {tid, tid+256}
    const int c0 = tid, c1 = tid + 256;
    const int r0 = c0 >> 2, r1 = c1 >> 2;
    const int g0 = ((c0 & 3) - ((r0 >> 1) & 3)) & 3;   // inverse swizzle
    const int g1 = ((c1 & 3) - ((r1 >> 1) & 3)) & 3;
    const signed char* gA0 = qx + (long)(m0 + r0) * K_DIM + g0 * 16;
    const signed char* gA1 = qx + (long)(m0 + r1) * K_DIM + g1 * 16;
    const signed char* gB0 = qw + (long)(n0 + r0) * K_DIM + g0 * 16;
    const signed char* gB1 = qw + (long)(n0 + r1) * K_DIM + g1 * 16;
    signed char* lA0 = &lA[c0 * 16];
    signed char* lA1 = &lA[c1 * 16];
    signed char* lB0 = &lB[c0 * 16];
    signed char* lB1 = &lB[c1 * 16];

    // fragment addresses: A[m=lane&15][k=(lane>>4)*16+j]
    const int fr = lane & 15;
    const int fq = lane >> 4;
    int offA[4], offB[4];
#pragma unroll
    for (int i = 0; i < 4; ++i) {
        int ra = wr + i * 16 + fr;
        offA[i] = ra * 64 + (((fq + (ra >> 1)) & 3) << 4);
        int rb = wc + i * 16 + fr;
        offB[i] = rb * 64 + (((fq + (rb >> 1)) & 3) << 4);
    }

    v4i acc[4][4];
#pragma unroll
    for (int i = 0; i < 4; ++i)
#pragma unroll
        for (int j = 0; j < 4; ++j) acc[i][j] = 0;

    for (int k0 = 0; k0 < K_DIM; k0 += 64) {
        __syncthreads();                 // prior iter's ds_reads done
        gl_lds16(gA0 + k0, lA0);
        gl_lds16(gA1 + k0, lA1);
        gl_lds16(gB0 + k0, lB0);
        gl_lds16(gB1 + k0, lB1);
        __syncthreads();                 // drains vmcnt: staging complete

        v4i a[4], b[4];
#pragma unroll
        for (int i = 0; i < 4; ++i) a[i] = *(const v4i*)&lA[offA[i]];
#pragma unroll
        for (int i = 0; i < 4; ++i) b[i] = *(const v4i*)&lB[offB[i]];
#pragma unroll
        for (int i = 0; i < 4; ++i)
#pragma unroll
            for (int j = 0; j < 4; ++j)
                acc[i][j] = __builtin_amdgcn_mfma_i32_16x16x64_i8(a[i], b[j], acc[i][j], 0, 0, 0);
    }

    // epilogue: C/D layout col=lane&15, row=(lane>>4)*4+reg (dtype-independent)
#pragma unroll
    for (int i = 0; i < 4; ++i) {
#pragma unroll
        for (int r = 0; r < 4; ++r) {
            const int m = m0 + wr + i * 16 + fq * 4 + r;
            const float sm = sx[m];
#pragma unroll
            for (int j = 0; j < 4; ++j) {
                const int n = n0 + wc + j * 16 + fr;
                out[(long)m * N_DIM + n] = (float)acc[i][j][r] * sm;
            }
        }
    }
}

extern "C" void kernel_launch(void* const* d_in, const int* in_sizes, int n_in,
                              void* d_out, int out_size, void* d_ws, size_t ws_size,
                              hipStream_t stream) {
    const float* x = (const float*)d_in[0];        // (4,2048,4096) fp32
    const float* w = (const float*)d_in[1];        // (16384,4096) fp32
    float* out = (float*)d_out;                    // (4,2048,16384) fp32
    char* ws = (char*)d_ws;

    // workspace layout (~100.7 MB total)
    double* part         = (double*)(ws);                        // 8 KB
    float*  wscale       = (float*)(ws + 8192);                  // 4 B
    float*  sx           = (float*)(ws + 16384);                 // 32 KB
    signed char* qx      = (signed char*)(ws + 65536);                    // 32 MB
    signed char* qw      = (signed char*)(ws + 65536 + (size_t)33554432); // 64 MB

    wabs_partial_k<<<1024, 256, 0, stream>>>(w, part);
    wscale_final_k<<<1, 256, 0, stream>>>(part, wscale);
    wquant_k<<<16384, 256, 0, stream>>>(w, qw, wscale);
    xquant_k<<<8192, 256, 0, stream>>>(x, qx, sx, wscale);
    dim3 grid(M_DIM / 128, N_DIM / 128);
    gemm_k<<<grid, 256, 0, stream>>>(qx, qw, sx, out);
}